// Round 15
// baseline (54.569 us; speedup 1.0000x reference)
//
#include <hip/hip_runtime.h>
#include <math.h>

#define H 1024
#define W 1024
#define OH 1016
#define OW 1016
#define BH 16          // output rows per band; 64 bands (last has 8 valid rows)
#define NBANDS 64
#define NCHUNK 5       // chunks advance 248 cols; top 2 lanes = halo providers
#define CSTR 248
#define NIMG 8
#define NWG (NBANDS*NCHUNK*NIMG)   // 2560, divisible by 8 (bijective XCD swizzle)
#define EPS 1e-6f
#define EPS2 1e-12f    // (vv<EPS) <=> (vx*vy<EPS2)
#define INV25 (1.0f/25.0f)

// R15: cooperative loading. R14's lane loaded a 12-float span (3 float4) per
// row per array = 2.9x redundancy -> ~18KB/wave-iter through L1 (64B/cyc/CU)
// ~= 19us of pure L1 delivery. Now each lane loads ONLY its own float4; the
// 5-wide horizontal windows get halo values via __shfl_down(.,1):
//   cs halo (4 shfl/arr), center halo (2), dx halo (4), ring-old halo (4).
// Seam eliminated structurally: chunk stride 248 (not 256) -> lanes 62,63 are
// halo-only providers. dx garbage exists only at lane63 (its cs-halo shfl
// clamps); it reaches only lane62's cp -> lanes 62,63 never store
// (guard t<=61 && j0<=1012). Right-edge (chunk4 tail) loads clamp to col
// 1020; garbage flows only into non-stored lanes (verified chain).
// Keeps: BH=16 + tail break, rsq finalize, XCD swizzle, LDS dx-ring
// (per-lane float4, contiguous = conflict-free; read-own-then-write-own
// ordering as R8/R14), launch_bounds(64,2).
// Sentinels: WRITE must stay 96774 KB (spill), conflicts ~0.

__device__ __forceinline__ float4 ld4(const float* p){ return *reinterpret_cast<const float4*>(p); }
__device__ __forceinline__ void st4(float* p, float4 v){ *reinterpret_cast<float4*>(p) = v; }

__global__ __launch_bounds__(64, 2)
void yiq_gngc_coop(const float* __restrict__ x, const float* __restrict__ y,
                   float* __restrict__ out, long long Nper)
{
    __shared__ __align__(16) float4 ring[5][2][64];   // 10240 B, per-lane float4
    const int t = (int)threadIdx.x;

    // ---- XCD-aware bijective swizzle (NWG % 8 == 0) ----
    const int wg  = (int)blockIdx.x;
    const int nid = (wg & 7) * (NWG / 8) + (wg >> 3);
    const int band  = nid % NBANDS;
    const int rest  = nid / NBANDS;        // 0..39
    const int chunk = rest % NCHUNK;
    const int b     = rest / NCHUNK;       // image 0..7

    const int jc = chunk * CSTR;
    const int j0 = jc + 4 * t;                         // logical cols j0..j0+3
    const int j0L = (j0 > W - 4) ? (W - 4) : j0;       // load clamp (chunk4 tail)
    const bool dostore = (t <= 61) && (j0 <= OW - 4);  // lanes 62,63 = halo-only
    const int i0 = band * BH;                          // 0..1008
    const float* xb = x + (size_t)b * (H * W) + j0L;
    const float* yb = y + (size_t)b * (H * W) + j0L;

    float csx[4], csy[4];
    float cp1[8], cp2[8], cp3[8];
    #pragma unroll
    for (int k = 0; k < 4; ++k) { csx[k] = 0.f; csy[k] = 0.f; }
    #pragma unroll
    for (int k = 0; k < 8; ++k) { cp1[k] = 0.f; cp2[k] = 0.f; cp3[k] = 0.f; }

    // ---- initial input column sums over rows i0..i0+4 ----
    #pragma unroll
    for (int r = 0; r < 5; ++r) {
        float4 vx = ld4(xb + (size_t)(i0 + r) * W);
        float4 vy = ld4(yb + (size_t)(i0 + r) * W);
        csx[0] += vx.x; csx[1] += vx.y; csx[2] += vx.z; csx[3] += vx.w;
        csy[0] += vy.x; csy[1] += vy.y; csy[2] += vy.z; csy[3] += vy.w;
    }

    // ---- zero ring slot 4 (the "row -1" subtracted at it=0) ----
    {
        float4 z = make_float4(0.f, 0.f, 0.f, 0.f);
        ring[4][0][t] = z; ring[4][1][t] = z;
    }

    // dx/dy compute from cs + shfl halo. dxn[k] = dx at col j0+k.
    // window for dxn[k]: cs cols j0+k..j0+k+4; w[4..7] come from lane t+1.
    // center for dxn[k]: x at col j0+k+2: own .z/.w then lane t+1's .x/.y.
#define COMPUTE_D(dn, cs, c4)                                              \
    {                                                                      \
        float w4 = __shfl_down(cs[0], 1), w5 = __shfl_down(cs[1], 1);      \
        float w6 = __shfl_down(cs[2], 1), w7 = __shfl_down(cs[3], 1);      \
        float ce2 = __shfl_down(c4.x, 1), ce3 = __shfl_down(c4.y, 1);      \
        float m = cs[1] + cs[2] + cs[3];                                   \
        dn[0] = c4.z - (cs[0] + m + w4) * INV25;                           \
        dn[1] = c4.w - (m + w4 + w5) * INV25;                              \
        dn[2] = ce2 - (cs[2] + cs[3] + w4 + w5 + w6) * INV25;              \
        dn[3] = ce3 - (cs[3] + w4 + w5 + w6 + w7) * INV25;                 \
    }

    // ---- prime dx/dy rows i0..i0+3 into ring slots 0..3; accumulate cp ----
    #pragma unroll
    for (int pr = 0; pr < 4; ++pr) {
        float4 xc = ld4(xb + (size_t)(i0 + pr + 2) * W);
        float4 yc = ld4(yb + (size_t)(i0 + pr + 2) * W);
        float4 nx = ld4(xb + (size_t)(i0 + pr + 5) * W);
        float4 ox = ld4(xb + (size_t)(i0 + pr) * W);
        float4 ny = ld4(yb + (size_t)(i0 + pr + 5) * W);
        float4 oy = ld4(yb + (size_t)(i0 + pr) * W);

        float dxn[4], dyn[4];
        COMPUTE_D(dxn, csx, xc);
        COMPUTE_D(dyn, csy, yc);
        float dhx[4], dhy[4];
        #pragma unroll
        for (int m = 0; m < 4; ++m) { dhx[m] = __shfl_down(dxn[m], 1); dhy[m] = __shfl_down(dyn[m], 1); }

        ring[pr][0][t] = make_float4(dxn[0], dxn[1], dxn[2], dxn[3]);
        ring[pr][1][t] = make_float4(dyn[0], dyn[1], dyn[2], dyn[3]);

        #pragma unroll
        for (int k = 0; k < 4; ++k) {
            cp1[k] += dxn[k] * dyn[k];  cp1[4 + k] += dhx[k] * dhy[k];
            cp2[k] += dxn[k] * dxn[k];  cp2[4 + k] += dhx[k] * dhx[k];
            cp3[k] += dyn[k] * dyn[k];  cp3[4 + k] += dhy[k] * dhy[k];
        }
        // slide cs: add row i0+pr+5, drop row i0+pr
        csx[0] += nx.x - ox.x; csx[1] += nx.y - ox.y; csx[2] += nx.z - ox.z; csx[3] += nx.w - ox.w;
        csy[0] += ny.x - oy.x; csy[1] += ny.y - oy.y; csy[2] += ny.z - oy.z; csy[3] += ny.w - oy.w;
    }

    float* ob = out + (size_t)b * ((size_t)OH * OW) + j0;
    int s = 4;   // rotating ring slot (dropped row i-1 == new row i+4)

    // ---- main loop: output rows i0..i0+BH-1 (tail band breaks at OH) ----
    #pragma unroll 4
    for (int it = 0; it < BH; ++it) {
        const int i = i0 + it;
        if (i >= OH) break;                           // block-uniform (tail band)
        const bool slide = (it < BH - 1) && (i < OH - 1);

        // all loads batched at top (center i+6, new i+9 <=1023, old i+4)
        float4 xc = ld4(xb + (size_t)(i + 6) * W);
        float4 yc = ld4(yb + (size_t)(i + 6) * W);
        float4 nx, ox, ny, oy;
        if (slide) {
            nx = ld4(xb + (size_t)(i + 9) * W);
            ox = ld4(xb + (size_t)(i + 4) * W);
            ny = ld4(yb + (size_t)(i + 9) * W);
            oy = ld4(yb + (size_t)(i + 4) * W);
        }

        // old dx/dy (row i-1): own 4 from ring (read-before-write, same lane
        // same address -> ordered), halo via shfl (lane63 garbage -> unstored)
        float4 orx = ring[s][0][t];
        float4 ory = ring[s][1][t];
        float ohx0 = __shfl_down(orx.x, 1), ohx1 = __shfl_down(orx.y, 1);
        float ohx2 = __shfl_down(orx.z, 1), ohx3 = __shfl_down(orx.w, 1);
        float ohy0 = __shfl_down(ory.x, 1), ohy1 = __shfl_down(ory.y, 1);
        float ohy2 = __shfl_down(ory.z, 1), ohy3 = __shfl_down(ory.w, 1);

        // new dx/dy row i+4
        float dxn[4], dyn[4];
        COMPUTE_D(dxn, csx, xc);
        COMPUTE_D(dyn, csy, yc);
        float dhx[4], dhy[4];
        #pragma unroll
        for (int m = 0; m < 4; ++m) { dhx[m] = __shfl_down(dxn[m], 1); dhy[m] = __shfl_down(dyn[m], 1); }

        ring[s][0][t] = make_float4(dxn[0], dxn[1], dxn[2], dxn[3]);
        ring[s][1][t] = make_float4(dyn[0], dyn[1], dyn[2], dyn[3]);

        // slide product column sums: + new row, - old row
        float odx[8] = {orx.x, orx.y, orx.z, orx.w, ohx0, ohx1, ohx2, ohx3};
        float ody[8] = {ory.x, ory.y, ory.z, ory.w, ohy0, ohy1, ohy2, ohy3};
        float ndx[8] = {dxn[0], dxn[1], dxn[2], dxn[3], dhx[0], dhx[1], dhx[2], dhx[3]};
        float ndy[8] = {dyn[0], dyn[1], dyn[2], dyn[3], dhy[0], dhy[1], dhy[2], dhy[3]};
        #pragma unroll
        for (int k = 0; k < 8; ++k) {
            cp1[k] += ndx[k] * ndy[k] - odx[k] * ody[k];
            cp2[k] += ndx[k] * ndx[k] - odx[k] * odx[k];
            cp3[k] += ndy[k] * ndy[k] - ody[k] * ody[k];
        }

        // finalize output row i, cols j0..j0+3 (fast rsq path)
        if (dostore) {
            float co[4], vv[4], cc[4];
            #pragma unroll
            for (int q = 0; q < 4; ++q) {
                float c_ = (cp1[q] + cp1[q+1] + cp1[q+2] + cp1[q+3] + cp1[q+4]) * INV25;
                float vx = (cp2[q] + cp2[q+1] + cp2[q+2] + cp2[q+3] + cp2[q+4]) * INV25;
                float vy = (cp3[q] + cp3[q+1] + cp3[q+2] + cp3[q+3] + cp3[q+4]) * INV25;
                float sp = vx * vy;
                bool lo  = sp < EPS2;
                float r  = __builtin_amdgcn_rsqf(sp);
                float cr = c_ * r;
                cr = cr < 0.f ? 0.f : (cr > 1.f ? 1.f : cr);
                co[q] = lo ? 0.f : cr;
                vv[q] = lo ? EPS : sp * r;
                cc[q] = lo ? 0.f : c_;
            }
            float* o = ob + (size_t)i * OW;
            st4(o,            make_float4(co[0], co[1], co[2], co[3]));
            st4(o + Nper,     make_float4(vv[0], vv[1], vv[2], vv[3]));
            st4(o + 2 * Nper, make_float4(cc[0], cc[1], cc[2], cc[3]));
        }

        // slide input column sums
        if (slide) {
            csx[0] += nx.x - ox.x; csx[1] += nx.y - ox.y; csx[2] += nx.z - ox.z; csx[3] += nx.w - ox.w;
            csy[0] += ny.x - oy.x; csy[1] += ny.y - oy.y; csy[2] += ny.z - oy.z; csy[3] += ny.w - oy.w;
        }
        s = (s == 4) ? 0 : s + 1;
    }
}

extern "C" void kernel_launch(void* const* d_in, const int* in_sizes, int n_in,
                              void* d_out, int out_size, void* d_ws, size_t ws_size,
                              hipStream_t stream) {
    const float* x = (const float*)d_in[0];
    const float* y = (const float*)d_in[1];
    // mask (d_in[2]) unused by the reference's channels==1 path
    float* out = (float*)d_out;
    const long long Nper = (long long)out_size / 3;   // elements per output array
    yiq_gngc_coop<<<dim3(NWG), dim3(64), 0, stream>>>(x, y, out, Nper);
}